// Round 1
// baseline (2137.952 us; speedup 1.0000x reference)
//
#include <hip/hip_runtime.h>
#include <math.h>

// LSTM: B=4096 independent chains, T=512, I=1, H=64, O=1, fp32.
// One workgroup (256 thr = 4 waves) per batch element.
// Thread tid owns gate row n = tid (gate group g = tid>>6 in PyTorch order
// i,f,g,o; hidden unit j = tid&63). Its 64-wide w_hh row stays in VGPRs.
// h is broadcast from LDS (same-address ds_read_b128, conflict-free).
// Wave 0 owns the c-state and does the per-step activation/update.

#define BB 4096
#define TT 512
#define HH 64
#define G4 256

__device__ __forceinline__ float sigmoidf_(float x) {
    return 1.0f / (1.0f + __expf(-x));
}
__device__ __forceinline__ float tanhf_(float x) {
    // tanh(x) = 1 - 2/(1+e^{2x}); |gate| <= ~9 so no overflow concerns
    return 1.0f - 2.0f / (1.0f + __expf(2.0f * x));
}

__global__ __launch_bounds__(256, 4) void lstm_kernel(
    const float* __restrict__ x,      // [B, T]  (I==1)
    const float* __restrict__ w_ih,   // [256]   (I==1)
    const float* __restrict__ w_hh,   // [256, 64]
    const float* __restrict__ b_ih,   // [256]
    const float* __restrict__ b_hh,   // [256]
    const float* __restrict__ w_out,  // [64]    (O==1)
    const float* __restrict__ b_out,  // [1]
    float* __restrict__ out)          // [B]
{
    __shared__ __align__(16) float sh_x[TT];
    __shared__ __align__(16) float sh_h[HH];
    __shared__ __align__(16) float sh_g[G4];

    const int b   = blockIdx.x;
    const int tid = threadIdx.x;
    const int g   = tid >> 6;   // wave id == gate group (i,f,g,o)
    const int j   = tid & 63;   // hidden unit
    const int n   = tid;        // gate row index g*64+j

    // cooperative, coalesced load of this batch's input sequence
    {
        const float* xb = x + (size_t)b * TT;
        sh_x[tid]       = xb[tid];
        sh_x[tid + 256] = xb[tid + 256];
    }
    if (tid < HH) sh_h[tid] = 0.0f;

    // preload w_hh row n into registers (16x float4; row is 256B-aligned)
    float w[HH];
    {
        const float4* wr = (const float4*)(w_hh + n * HH);
        #pragma unroll
        for (int k4 = 0; k4 < HH / 4; ++k4) {
            float4 v = wr[k4];
            w[4 * k4 + 0] = v.x;
            w[4 * k4 + 1] = v.y;
            w[4 * k4 + 2] = v.z;
            w[4 * k4 + 3] = v.w;
        }
    }
    const float wih  = w_ih[n];
    const float bias = b_ih[n] + b_hh[n];

    float c = 0.0f;  // c-state of unit j, valid on wave 0 only
    __syncthreads();

    for (int t = 0; t < TT; ++t) {
        // gates[n] = x[b,t]*w_ih[n] + bias[n] + sum_k h[k]*w_hh[n,k]
        // 4 independent accumulator chains for ILP
        float a0 = fmaf(sh_x[t], wih, bias);
        float a1 = 0.0f, a2 = 0.0f, a3 = 0.0f;
        const float4* h4 = (const float4*)sh_h;
        #pragma unroll
        for (int k4 = 0; k4 < HH / 4; ++k4) {
            float4 hv = h4[k4];  // broadcast read, conflict-free
            a0 = fmaf(hv.x, w[4 * k4 + 0], a0);
            a1 = fmaf(hv.y, w[4 * k4 + 1], a1);
            a2 = fmaf(hv.z, w[4 * k4 + 2], a2);
            a3 = fmaf(hv.w, w[4 * k4 + 3], a3);
        }
        sh_g[n] = (a0 + a1) + (a2 + a3);
        __syncthreads();

        if (g == 0) {  // wave 0 updates the cell
            float gi = sigmoidf_(sh_g[j]);
            float gf = sigmoidf_(sh_g[HH + j]);
            float gg = tanhf_(sh_g[2 * HH + j]);
            float go = sigmoidf_(sh_g[3 * HH + j]);
            c = fmaf(gf, c, gi * gg);
            sh_h[j] = go * tanhf_(c);
        }
        __syncthreads();
    }

    // out[b] = dot(h_T, w_out) + b_out  (wave-0 shuffle reduction)
    if (g == 0) {
        float v = sh_h[j] * w_out[j];
        #pragma unroll
        for (int off = 32; off > 0; off >>= 1)
            v += __shfl_down(v, off);
        if (j == 0) out[b] = v + b_out[0];
    }
}

extern "C" void kernel_launch(void* const* d_in, const int* in_sizes, int n_in,
                              void* d_out, int out_size, void* d_ws, size_t ws_size,
                              hipStream_t stream) {
    const float* x     = (const float*)d_in[0];
    const float* w_ih  = (const float*)d_in[1];
    const float* w_hh  = (const float*)d_in[2];
    const float* b_ih  = (const float*)d_in[3];
    const float* b_hh  = (const float*)d_in[4];
    const float* w_out = (const float*)d_in[5];
    const float* b_out = (const float*)d_in[6];
    float* out = (float*)d_out;

    lstm_kernel<<<BB, 256, 0, stream>>>(x, w_ih, w_hh, b_ih, b_hh,
                                        w_out, b_out, out);
}

// Round 2
// 384.853 us; speedup vs baseline: 5.5552x; 5.5552x over previous
//
#include <hip/hip_runtime.h>

// LSTM B=4096, T=512, I=1, H=64, O=1 (fp32 in/out).
// MFMA redesign: block = 256 thr (4 waves) handles MB=16 batches; grid = 256.
// Recurrence gates = H @ W_hh^T via mfma_f32_16x16x32_f16 with split:
//   gates = (h_hi + h_lo) * W_hi   (h split exact; W fp16-rounded once)
// Wave w owns N-tiles {w, w+4, w+8, w+12} -> one 16-col tile per gate group.
// Consequence: all 4 gates of cell (m, j=16w+(lane&15)) live in the SAME lane
// (lane = (m>>2)*16 + (j&15), reg = m&3) -> activations run directly on the
// MFMA accumulators; only h round-trips LDS each step.
// MFMA layouts (m89/m120-verified):
//   A[m=lane&15][k=(lane>>4)*8+j]   B[k=(lane>>4)*8+j][n=lane&15]
//   D[m=(lane>>4)*4+r][n=lane&15]

#define TT   512
#define MB   16
#define HSTR 68   // h_lds row stride (dwords): 16B-aligned (68*4=272=16*17), conflict-free

typedef _Float16 f16x8 __attribute__((ext_vector_type(8)));
typedef float    f32x4 __attribute__((ext_vector_type(4)));

#define MFMA16(a, b, c) __builtin_amdgcn_mfma_f32_16x16x32_f16((a), (b), (c), 0, 0, 0)

__device__ __forceinline__ float rcp_(float x) { return __builtin_amdgcn_rcpf(x); }
__device__ __forceinline__ float sigmoid_(float x) { return rcp_(1.0f + __expf(-x)); }
__device__ __forceinline__ float tanh_(float x) { return 1.0f - 2.0f * rcp_(1.0f + __expf(2.0f * x)); }

__device__ __forceinline__ f16x8 cvt8(const float4& u0, const float4& u1) {
    f16x8 r;
    r[0] = (_Float16)u0.x; r[1] = (_Float16)u0.y; r[2] = (_Float16)u0.z; r[3] = (_Float16)u0.w;
    r[4] = (_Float16)u1.x; r[5] = (_Float16)u1.y; r[6] = (_Float16)u1.z; r[7] = (_Float16)u1.w;
    return r;
}

__device__ __forceinline__ void split8(const float4& u0, const float4& u1,
                                       f16x8& hi, f16x8& lo) {
    float tmp[8] = {u0.x, u0.y, u0.z, u0.w, u1.x, u1.y, u1.z, u1.w};
    #pragma unroll
    for (int i = 0; i < 8; ++i) {
        _Float16 h = (_Float16)tmp[i];
        hi[i] = h;
        lo[i] = (_Float16)(tmp[i] - (float)h);
    }
}

__global__ __launch_bounds__(256, 1) void lstm_mfma(
    const float* __restrict__ x,      // [4096, 512]  (I==1)
    const float* __restrict__ w_ih,   // [256]
    const float* __restrict__ w_hh,   // [256, 64]
    const float* __restrict__ b_ih,   // [256]
    const float* __restrict__ b_hh,   // [256]
    const float* __restrict__ w_out,  // [64]
    const float* __restrict__ b_out,  // [1]
    float* __restrict__ out)          // [4096]
{
    __shared__ __align__(16) float sh_x[TT * MB];     // [t][m]  32 KB
    __shared__ __align__(16) float h_lds[MB * HSTR];  // [m][k]  fp32

    const int tid = threadIdx.x;
    const int w   = tid >> 6;   // wave id 0..3
    const int L   = tid & 63;
    const int l16 = L & 15;
    const int h0  = L >> 4;     // 0..3
    const int b0  = blockIdx.x * MB;

    // ---- stage x transposed: sh_x[t][m] = x[b0+m][t] ----
    {
        const int q = tid >> 4;   // batch row 0..15
        const int l = tid & 15;
        const float* xr = x + (size_t)(b0 + q) * TT;
        #pragma unroll
        for (int c = 0; c < 8; ++c) {
            const int t0 = l * 4 + c * 64;
            float4 v = *(const float4*)(xr + t0);
            sh_x[(t0 + 0) * MB + q] = v.x;
            sh_x[(t0 + 1) * MB + q] = v.y;
            sh_x[(t0 + 2) * MB + q] = v.z;
            sh_x[(t0 + 3) * MB + q] = v.w;
        }
    }
    // ---- zero h ----
    for (int i = tid; i < MB * HSTR; i += 256) h_lds[i] = 0.0f;

    // ---- preload W_hh fragments (fp16-rounded), per wave's 8 frags ----
    // wave w, s-tile s (gate group s), K-tile kt:
    //   B[k][n] = w_hh[n][k], n = 16w + 64s + l16, k = kt*32 + h0*8 + j
    f16x8 Bf[4][2];
    float wihv[4], biasv[4];
    #pragma unroll
    for (int s = 0; s < 4; ++s) {
        const int n = 16 * w + 64 * s + l16;
        #pragma unroll
        for (int kt = 0; kt < 2; ++kt) {
            const float* p = w_hh + n * 64 + kt * 32 + h0 * 8;
            float4 u0 = *(const float4*)p;
            float4 u1 = *(const float4*)(p + 4);
            Bf[s][kt] = cvt8(u0, u1);
        }
        wihv[s]  = w_ih[n];
        biasv[s] = b_ih[n] + b_hh[n];
    }

    float cc[4] = {0.0f, 0.0f, 0.0f, 0.0f};  // c-state: cells (m=h0*4+r, j=16w+l16)
    const int jcol = 16 * w + l16;

    __syncthreads();

    for (int t = 0; t < TT; ++t) {
        // ---- read A rows (h) + x, all fp32 ----
        const float* hp = h_lds + l16 * HSTR + h0 * 8;
        float4 a00 = *(const float4*)(hp + 0);
        float4 a01 = *(const float4*)(hp + 4);
        float4 a10 = *(const float4*)(hp + 32);
        float4 a11 = *(const float4*)(hp + 36);
        float4 xv  = *(const float4*)(sh_x + t * MB + h0 * 4);
        __syncthreads();  // all reads done before anyone writes h below

        f16x8 ah0, al0, ah1, al1;
        split8(a00, a01, ah0, al0);
        split8(a10, a11, ah1, al1);

        f32x4 acc0 = {0.f, 0.f, 0.f, 0.f};
        f32x4 acc1 = {0.f, 0.f, 0.f, 0.f};
        f32x4 acc2 = {0.f, 0.f, 0.f, 0.f};
        f32x4 acc3 = {0.f, 0.f, 0.f, 0.f};
        acc0 = MFMA16(ah0, Bf[0][0], acc0);
        acc1 = MFMA16(ah0, Bf[1][0], acc1);
        acc2 = MFMA16(ah0, Bf[2][0], acc2);
        acc3 = MFMA16(ah0, Bf[3][0], acc3);
        acc0 = MFMA16(al0, Bf[0][0], acc0);
        acc1 = MFMA16(al0, Bf[1][0], acc1);
        acc2 = MFMA16(al0, Bf[2][0], acc2);
        acc3 = MFMA16(al0, Bf[3][0], acc3);
        acc0 = MFMA16(ah1, Bf[0][1], acc0);
        acc1 = MFMA16(ah1, Bf[1][1], acc1);
        acc2 = MFMA16(ah1, Bf[2][1], acc2);
        acc3 = MFMA16(ah1, Bf[3][1], acc3);
        acc0 = MFMA16(al1, Bf[0][1], acc0);
        acc1 = MFMA16(al1, Bf[1][1], acc1);
        acc2 = MFMA16(al1, Bf[2][1], acc2);
        acc3 = MFMA16(al1, Bf[3][1], acc3);

        // ---- activations directly on accumulators; cells (m=h0*4+r, jcol) ----
        float xm[4] = {xv.x, xv.y, xv.z, xv.w};
        #pragma unroll
        for (int r = 0; r < 4; ++r) {
            float gi = acc0[r] + fmaf(xm[r], wihv[0], biasv[0]);
            float gf = acc1[r] + fmaf(xm[r], wihv[1], biasv[1]);
            float gg = acc2[r] + fmaf(xm[r], wihv[2], biasv[2]);
            float go = acc3[r] + fmaf(xm[r], wihv[3], biasv[3]);
            float i_ = sigmoid_(gi);
            float f_ = sigmoid_(gf);
            float g_ = tanh_(gg);
            float o_ = sigmoid_(go);
            cc[r] = fmaf(f_, cc[r], i_ * g_);
            float hv = o_ * tanh_(cc[r]);
            h_lds[(h0 * 4 + r) * HSTR + jcol] = hv;
        }
        __syncthreads();  // h writes visible before next iteration's reads
    }

    // ---- epilogue: out[b0+m] = dot(h_T[m], w_out) + b_out ----
    const float wo = w_out[L];
    #pragma unroll
    for (int q = 0; q < 4; ++q) {
        const int m = 4 * w + q;
        float v = h_lds[m * HSTR + L] * wo;
        #pragma unroll
        for (int off = 32; off; off >>= 1) v += __shfl_down(v, off);
        if (L == 0) out[b0 + m] = v + b_out[0];
    }
}

extern "C" void kernel_launch(void* const* d_in, const int* in_sizes, int n_in,
                              void* d_out, int out_size, void* d_ws, size_t ws_size,
                              hipStream_t stream) {
    const float* x     = (const float*)d_in[0];
    const float* w_ih  = (const float*)d_in[1];
    const float* w_hh  = (const float*)d_in[2];
    const float* b_ih  = (const float*)d_in[3];
    const float* b_hh  = (const float*)d_in[4];
    const float* w_out = (const float*)d_in[5];
    const float* b_out = (const float*)d_in[6];
    float* out = (float*)d_out;

    lstm_mfma<<<4096 / MB, 256, 0, stream>>>(x, w_ih, w_hh, b_ih, b_hh,
                                             w_out, b_out, out);
}